// Round 9
// baseline (286.467 us; speedup 1.0000x reference)
//
#include <hip/hip_runtime.h>

#define FIN 128
#define FHID 32
#define FOUT 64
#define MAXDEG 10
#define BSH 8              // dst bucket = dst >> 8 (256 dsts per bucket)
#define ACHUNK 4096        // edges per pass-A workgroup (16 per thread)
#define XPAD 136           // LDS row stride (bf16) for 128-k tiles
#define YPAD 40            // LDS row stride (bf16) for 32-k tiles: 80B, 16B-aligned
#define SRCBITS 20         // packed pair: src in bits 0..19 (requires N < 2^20), dst&255 in 20..27

typedef __attribute__((ext_vector_type(8))) short short8;
typedef __attribute__((ext_vector_type(4))) float f32x4;

// edge_index arrives as int32: layout [2, E] flat: src = ei[e], dst = ei[E + e].

__device__ __forceinline__ float bf2f(unsigned short u) {
    union { unsigned int i; float f; } c; c.i = ((unsigned int)u) << 16; return c.f;
}
__device__ __forceinline__ unsigned short f2bf(float f) {
    union { float f; unsigned int i; } c; c.f = f;
    unsigned int r = c.i + 0x7FFF + ((c.i >> 16) & 1);   // round-nearest-even
    return (unsigned short)(r >> 16);
}
__device__ __forceinline__ float bflo(unsigned int w) { return bf2f((unsigned short)(w & 0xffff)); }
__device__ __forceinline__ float bfhi(unsigned int w) { return bf2f((unsigned short)(w >> 16)); }
__device__ __forceinline__ unsigned int pk2(float lo, float hi) {
    return (unsigned int)f2bf(lo) | ((unsigned int)f2bf(hi) << 16);
}

// ---------- CSR build (bucket-hierarchical: NO per-edge global atomics) ----------

// Per-block LDS histogram over dst buckets; one global atomic per (block, bucket).
// Block 0 additionally prepacks the bucket-10 weights (hidden under other blocks).
__global__ __launch_bounds__(256) void k_bhistp(const int* __restrict__ ei, int E, int N,
                                                int* __restrict__ bcnt,
                                                const float* __restrict__ W1,
                                                const float* __restrict__ Wr1,
                                                const float* __restrict__ W2,
                                                const float* __restrict__ Wr2,
                                                unsigned short* __restrict__ wcat1,
                                                unsigned short* __restrict__ wcat2) {
    __shared__ int hist[1024];
    int K = ((N + 255) >> BSH);
    int t = threadIdx.x;
    long long cb = (long long)blockIdx.x * ACHUNK;
    for (int i = t; i < K; i += 256) hist[i] = 0;
    __syncthreads();
#pragma unroll
    for (int i = 0; i < 16; ++i) {
        long long e = cb + t + (long long)i * 256;
        if (e < E) {
            int ss = ei[e];
            int dd = ei[E + e];
            if ((unsigned)ss < (unsigned)N && (unsigned)dd < (unsigned)N)
                atomicAdd(&hist[dd >> BSH], 1);
        }
    }
    __syncthreads();
    for (int i = t; i < K; i += 256) {
        int h = hist[i];
        if (h) atomicAdd(&bcnt[i], h);
    }
    if (blockIdx.x == 0) {   // prepack: wcat1 [64n][128k], wcat2 [128n][32k]
        const float* W1b  = W1  + (size_t)MAXDEG * FIN * FHID;
        const float* Wr1b = Wr1 + (size_t)MAXDEG * FIN * FHID;
        const float* W2b  = W2  + (size_t)MAXDEG * FHID * FOUT;
        const float* Wr2b = Wr2 + (size_t)MAXDEG * FHID * FOUT;
        for (int i = 0; i < 32; ++i) {
            int idx = i * 256 + t;            // 8192
            int n = idx >> 7, k = idx & 127;
            float v = (n < 32) ? W1b[k * FHID + n] : Wr1b[k * FHID + (n - 32)];
            wcat1[idx] = f2bf(v);
        }
        for (int i = 0; i < 16; ++i) {
            int idx = i * 256 + t;            // 4096
            int n = idx >> 5, k = idx & 31;
            float v = (n < 64) ? W2b[k * FOUT + n] : Wr2b[k * FOUT + (n - 64)];
            wcat2[idx] = f2bf(v);
        }
    }
}

// Single-block exclusive scan of bcnt[0..K) -> bstart, gcur  (requires K <= 1024).
__global__ __launch_bounds__(1024) void k_scanb(const int* __restrict__ bcnt, int K,
                                                int* __restrict__ bstart,
                                                int* __restrict__ gcur) {
    __shared__ int tmp[1024];
    int t = threadIdx.x;
    int v = (t < K) ? bcnt[t] : 0;
    tmp[t] = v;
    __syncthreads();
    for (int off = 1; off < 1024; off <<= 1) {
        int a = (t >= off) ? tmp[t - off] : 0;
        __syncthreads();
        tmp[t] += a;
        __syncthreads();
    }
    if (t < K) { int s = tmp[t] - v; bstart[t] = s; gcur[t] = s; }
}

// Pass A: bucket edges by dst>>8 into packed pairs[], line-coalesced appends.
__global__ __launch_bounds__(256) void k_passA(const int* __restrict__ ei, int E, int N,
                                               int* __restrict__ gcur,
                                               unsigned int* __restrict__ pairs) {
    __shared__ int hist[1024];
    __shared__ int base[1024];
    int K = ((N + 255) >> BSH);
    int t = threadIdx.x;
    long long cb = (long long)blockIdx.x * ACHUNK;
    for (int i = t; i < K; i += 256) hist[i] = 0;
    __syncthreads();
    int sv[16], dv[16];
#pragma unroll
    for (int i = 0; i < 16; ++i) {
        sv[i] = -1; dv[i] = 0;
        long long e = cb + t + (long long)i * 256;
        if (e < E) {
            int ss = ei[e];
            int dd = ei[E + e];
            if ((unsigned)ss < (unsigned)N && (unsigned)dd < (unsigned)N) {
                sv[i] = ss; dv[i] = dd;
            }
        }
    }
#pragma unroll
    for (int i = 0; i < 16; ++i)
        if (sv[i] >= 0) atomicAdd(&hist[dv[i] >> BSH], 1);
    __syncthreads();
    for (int i = t; i < K; i += 256) {
        int h = hist[i];
        base[i] = h ? atomicAdd(&gcur[i], h) : 0;
    }
    __syncthreads();
    for (int i = t; i < K; i += 256) hist[i] = 0;
    __syncthreads();
#pragma unroll
    for (int i = 0; i < 16; ++i) {
        if (sv[i] >= 0) {
            int b = dv[i] >> BSH;
            int off = atomicAdd(&hist[b], 1);
            pairs[base[b] + off] = (unsigned int)sv[i] | ((unsigned int)(dv[i] & 255) << SRCBITS);
        }
    }
}

// Pass B2: per bucket -- derive per-node degrees in LDS (no global atomics),
// in-LDS exclusive scan -> row starts, write deg/cursor, scatter pairs->adj,
// and append deg<MAXDEG node ids to the compact flagged list.
__global__ __launch_bounds__(256) void k_passB2(const unsigned int* __restrict__ pairs,
                                                const int* __restrict__ bstart,
                                                const int* __restrict__ gcur,
                                                int* __restrict__ deg,
                                                int* __restrict__ cursor,
                                                int* __restrict__ adj,
                                                int* __restrict__ nflag,
                                                int* __restrict__ flist, int N) {
    __shared__ int cnt[256];
    __shared__ int scn[256];
    __shared__ int cur[256];
    __shared__ int fids[256];
    __shared__ int fcnt, fbase;
    int b = blockIdx.x;
    int lo = b << BSH;
    int t = threadIdx.x;
    int nvalid = min(256, N - lo);
    cnt[t] = 0;
    if (t == 0) fcnt = 0;
    int pstart = bstart[b];
    int pend = gcur[b];
    __syncthreads();
    for (int i = pstart + t; i < pend; i += 256)
        atomicAdd(&cnt[pairs[i] >> SRCBITS], 1);
    __syncthreads();
    int v = cnt[t];
    scn[t] = v;
    __syncthreads();
    for (int off = 1; off < 256; off <<= 1) {
        int a = (t >= off) ? scn[t - off] : 0;
        __syncthreads();
        scn[t] += a;
        __syncthreads();
    }
    int rowstart = pstart + scn[t] - v;
    cur[t] = rowstart;
    if (t < nvalid) {
        deg[lo + t] = v;
        cursor[lo + t] = rowstart + v;    // cursor = row END
        if (v < MAXDEG) { int p = atomicAdd(&fcnt, 1); fids[p] = lo + t; }
    }
    __syncthreads();
    if (t == 0 && fcnt > 0) fbase = atomicAdd(nflag, fcnt);
    __syncthreads();
    if (t < fcnt) flist[fbase + t] = fids[t];
    for (int i = pstart + t; i < pend; i += 256) {
        unsigned int pr = pairs[i];
        int pos = atomicAdd(&cur[pr >> SRCBITS], 1);
        adj[pos] = (int)(pr & ((1u << SRCBITS) - 1));
    }
}

// ---------- pre1 (MFMA): [z10 | r1] = x @ [W1[10] | Wr1[10]] + [0 | b1[10]] ----------
__global__ __launch_bounds__(256) void k_pre1m(const float* __restrict__ x,
                                               const unsigned short* __restrict__ wcat1,
                                               const float* __restrict__ b1,
                                               unsigned short* __restrict__ z10,
                                               unsigned short* __restrict__ r1, int N) {
    __shared__ __align__(16) unsigned short xt[64 * XPAD];
    __shared__ __align__(16) unsigned short wt[64 * XPAD];
    int t = threadIdx.x;
    int row0 = blockIdx.x * 64;
    {   // stage Wcat1 (8192 bf16 = 1024 uint4)
        const uint4* src = (const uint4*)wcat1;
#pragma unroll
        for (int i = 0; i < 4; ++i) {
            int idx = i * 256 + t;
            uint4 v = src[idx];
            int n = idx >> 4;
            int k = (idx & 15) * 8;
            *(uint4*)(wt + n * XPAD + k) = v;
        }
    }
    {   // stage x rows -> bf16
        int r = t >> 2;
        int c0 = (t & 3) * 32;
        int cr = min(row0 + r, N - 1);
        const float4* xs = (const float4*)(x + (size_t)cr * FIN + c0);
        unsigned short* dst = xt + r * XPAD + c0;
#pragma unroll
        for (int i = 0; i < 8; ++i) {
            float4 v = xs[i];
            ushort4 b;
            b.x = f2bf(v.x); b.y = f2bf(v.y); b.z = f2bf(v.z); b.w = f2bf(v.w);
            *(ushort4*)(dst + i * 4) = b;
        }
    }
    __syncthreads();
    int w = t >> 6, lane = t & 63;
    int m = lane & 15, quad = lane >> 4;
    const unsigned short* arow = xt + (w * 16 + m) * XPAD + quad * 8;
    short8 af[4];
#pragma unroll
    for (int kt = 0; kt < 4; ++kt) af[kt] = *(const short8*)(arow + kt * 32);
    f32x4 acc[4];
#pragma unroll
    for (int ct = 0; ct < 4; ++ct) acc[ct] = (f32x4){0.f, 0.f, 0.f, 0.f};
#pragma unroll
    for (int ct = 0; ct < 4; ++ct) {
        const unsigned short* brow = wt + (ct * 16 + m) * XPAD + quad * 8;
#pragma unroll
        for (int kt = 0; kt < 4; ++kt) {
            short8 bfr = *(const short8*)(brow + kt * 32);
            acc[ct] = __builtin_amdgcn_mfma_f32_16x16x32_bf16(af[kt], bfr, acc[ct], 0, 0, 0);
        }
    }
    int rbase = row0 + w * 16 + quad * 4;
#pragma unroll
    for (int ct = 0; ct < 4; ++ct) {
        float bias = (ct >= 2) ? b1[MAXDEG * FHID + (ct - 2) * 16 + m] : 0.f;
#pragma unroll
        for (int rg = 0; rg < 4; ++rg) {
            int n = rbase + rg;
            if (n < N) {
                float v = acc[ct][rg];
                if (ct < 2) z10[(size_t)n * FHID + ct * 16 + m] = f2bf(v);
                else        r1[(size_t)n * FHID + (ct - 2) * 16 + m] = f2bf(v + bias);
            }
        }
    }
}

// ---------- single-node 16-lane/edge gather (fixup paths) ----------
__device__ __forceinline__ void gather16(const unsigned short* __restrict__ rows,
                                         const int* __restrict__ adj,
                                         int e0, int e1, int cnt, int lane,
                                         float& a0, float& a1) {
    int e = lane >> 4, f2 = lane & 15;
    int sidx = adj[min(e0 + lane, e1 - 1)];
    const unsigned short* rb = rows + f2 * 2;
    int nfull = cnt >> 4;
    for (int c = 0; c < nfull; ++c) {
        int i0 = c * 16 + e;
        int s0 = __shfl(sidx, i0);
        int s1 = __shfl(sidx, i0 + 4);
        int s2 = __shfl(sidx, i0 + 8);
        int s3 = __shfl(sidx, i0 + 12);
        unsigned int w0 = *(const unsigned int*)(rb + (size_t)s0 * FHID);
        unsigned int w1 = *(const unsigned int*)(rb + (size_t)s1 * FHID);
        unsigned int w2 = *(const unsigned int*)(rb + (size_t)s2 * FHID);
        unsigned int w3 = *(const unsigned int*)(rb + (size_t)s3 * FHID);
        a0 += bflo(w0); a1 += bfhi(w0);
        a0 += bflo(w1); a1 += bfhi(w1);
        a0 += bflo(w2); a1 += bfhi(w2);
        a0 += bflo(w3); a1 += bfhi(w3);
    }
    if (cnt & 15) {
        int i0 = nfull * 16 + e;
        int i1 = i0 + 4, i2 = i0 + 8, i3 = i0 + 12;
        int s0 = __shfl(sidx, min(i0, cnt - 1));
        int s1 = __shfl(sidx, min(i1, cnt - 1));
        int s2 = __shfl(sidx, min(i2, cnt - 1));
        int s3 = __shfl(sidx, min(i3, cnt - 1));
        unsigned int w0 = *(const unsigned int*)(rb + (size_t)s0 * FHID);
        unsigned int w1 = *(const unsigned int*)(rb + (size_t)s1 * FHID);
        unsigned int w2 = *(const unsigned int*)(rb + (size_t)s2 * FHID);
        unsigned int w3 = *(const unsigned int*)(rb + (size_t)s3 * FHID);
        float c0 = (i0 < cnt) ? 1.f : 0.f;
        float c1 = (i1 < cnt) ? 1.f : 0.f;
        float c2 = (i2 < cnt) ? 1.f : 0.f;
        float c3 = (i3 < cnt) ? 1.f : 0.f;
        a0 = fmaf(c0, bflo(w0), a0); a1 = fmaf(c0, bfhi(w0), a1);
        a0 = fmaf(c1, bflo(w1), a0); a1 = fmaf(c1, bfhi(w1), a1);
        a0 = fmaf(c2, bflo(w2), a0); a1 = fmaf(c2, bfhi(w2), a1);
        a0 = fmaf(c3, bflo(w3), a0); a1 = fmaf(c3, bfhi(w3), a1);
    }
    for (int k = e0 + 64 + e; k < e1; k += 4) {    // rare tail (deg>64)
        int s = adj[k];
        unsigned int w = *(const unsigned int*)(rb + (size_t)s * FHID);
        a0 += bflo(w); a1 += bfhi(w);
    }
}

// ---------- 4-node interleaved gather: 16 loads in flight per chunk ----------
// Node i accumulates into a0[i],a1[i]. cnt[i]==0 disables node i (loads degenerate
// to one broadcast address, contributions masked to 0). All arrays indexed by
// unroll-constant indices only (register-resident).
__device__ __forceinline__ void gather16x4(const unsigned short* __restrict__ rows,
                                           const int* __restrict__ adj,
                                           const int* e0, const int* e1, const int* cnt,
                                           int lane, float* a0, float* a1) {
    int e2 = lane >> 4, f2 = lane & 15;
    const unsigned short* rb = rows + f2 * 2;
    int cm1[4], sidx[4];
    int maxc = 0;
#pragma unroll
    for (int i = 0; i < 4; ++i) {
        cm1[i] = max(cnt[i] - 1, 0);
        sidx[i] = adj[e0[i] + min(lane, cm1[i])];
        maxc = max(maxc, cnt[i]);
    }
    int nch = (maxc + 15) >> 4;
    for (int c = 0; c < nch; ++c) {
        int i0 = c * 16 + e2;
        int i1 = i0 + 4, i2 = i0 + 8, i3 = i0 + 12;
#pragma unroll
        for (int i = 0; i < 4; ++i) {
            int s0 = __shfl(sidx[i], min(i0, cm1[i]));
            int s1 = __shfl(sidx[i], min(i1, cm1[i]));
            int s2 = __shfl(sidx[i], min(i2, cm1[i]));
            int s3 = __shfl(sidx[i], min(i3, cm1[i]));
            unsigned int w0 = *(const unsigned int*)(rb + (size_t)s0 * FHID);
            unsigned int w1 = *(const unsigned int*)(rb + (size_t)s1 * FHID);
            unsigned int w2 = *(const unsigned int*)(rb + (size_t)s2 * FHID);
            unsigned int w3 = *(const unsigned int*)(rb + (size_t)s3 * FHID);
            float c0 = (i0 < cnt[i]) ? 1.f : 0.f;
            float c1 = (i1 < cnt[i]) ? 1.f : 0.f;
            float c2 = (i2 < cnt[i]) ? 1.f : 0.f;
            float c3 = (i3 < cnt[i]) ? 1.f : 0.f;
            a0[i] = fmaf(c0, bflo(w0), a0[i]); a1[i] = fmaf(c0, bfhi(w0), a1[i]);
            a0[i] = fmaf(c1, bflo(w1), a0[i]); a1[i] = fmaf(c1, bfhi(w1), a1[i]);
            a0[i] = fmaf(c2, bflo(w2), a0[i]); a1[i] = fmaf(c2, bfhi(w2), a1[i]);
            a0[i] = fmaf(c3, bflo(w3), a0[i]); a1[i] = fmaf(c3, bfhi(w3), a1[i]);
        }
    }
#pragma unroll
    for (int i = 0; i < 4; ++i) {
        for (int k = e0[i] + 64 + e2; k < e1[i]; k += 4) {   // rare tail (deg>64)
            int s = adj[k];
            unsigned int w = *(const unsigned int*)(rb + (size_t)s * FHID);
            a0[i] += bflo(w); a1[i] += bfhi(w);
        }
    }
}

// select array element by runtime g (0..3) via cndmask chain (no dynamic indexing)
__device__ __forceinline__ float sel4(const float* a, int g) {
    float lo = (g & 1) ? a[1] : a[0];
    float hi = (g & 1) ? a[3] : a[2];
    return (g & 2) ? hi : lo;
}
__device__ __forceinline__ int sel4i(const int* a, int g) {
    int lo = (g & 1) ? a[1] : a[0];
    int hi = (g & 1) ? a[3] : a[2];
    return (g & 2) ? hi : lo;
}

// ---------- layer1 fused: fast blocks gather z10 (4 nodes/wave); tail blocks deg<10 fixup ----------
__global__ __launch_bounds__(256) void k_layer1x(const unsigned short* __restrict__ z10,
                                                 const unsigned short* __restrict__ r1,
                                                 const int* __restrict__ deg,
                                                 const int* __restrict__ cursor,
                                                 const int* __restrict__ adj,
                                                 const float* __restrict__ x,
                                                 const float* __restrict__ W1,
                                                 const float* __restrict__ b1,
                                                 const float* __restrict__ Wr1,
                                                 const int* __restrict__ nflag,
                                                 const int* __restrict__ flist,
                                                 unsigned short* __restrict__ out1,
                                                 int N, int nbFast) {
    int t = threadIdx.x;
    int lane = t & 63;
    if ((int)blockIdx.x < nbFast) {
        int nb = blockIdx.x * 16 + (t >> 6) * 4;   // 4 nodes per wave
        if (nb >= N) return;
        int nl = min(nb + (lane & 3), N - 1);
        int dl = deg[nl];
        int cl = cursor[nl];
        int dg[4], e1v[4], e0v[4], cntv[4];
#pragma unroll
        for (int i = 0; i < 4; ++i) {
            dg[i] = __shfl(dl, i);
            e1v[i] = __shfl(cl, i);
            bool ok = (nb + i < N) && (dg[i] >= MAXDEG);   // deg<10 handled by fix blocks
            cntv[i] = ok ? min(dg[i], 64) : 0;
            e0v[i] = e1v[i] - dg[i];
            if (!ok) e1v[i] = e0v[i];                      // disable deg>64 tail too
        }
        if ((cntv[0] | cntv[1] | cntv[2] | cntv[3]) == 0) return;
        float a0[4] = {0.f, 0.f, 0.f, 0.f};
        float a1[4] = {0.f, 0.f, 0.f, 0.f};
        gather16x4(z10, adj, e0v, e1v, cntv, lane, a0, a1);
#pragma unroll
        for (int i = 0; i < 4; ++i) {
            a0[i] += __shfl_xor(a0[i], 16); a1[i] += __shfl_xor(a1[i], 16);
            a0[i] += __shfl_xor(a0[i], 32); a1[i] += __shfl_xor(a1[i], 32);
        }
        int g = lane >> 4, f2 = lane & 15;
        int cg = sel4i(cntv, g);
        if (cg > 0) {
            int ng = nb + g;
            float v0 = sel4(a0, g), v1 = sel4(a1, g);
            unsigned int rv = *(const unsigned int*)(r1 + (size_t)ng * FHID + f2 * 2);
            unsigned int w = pk2(fmaxf(v0 + bflo(rv), 0.f), fmaxf(v1 + bfhi(rv), 0.f));
            *(unsigned int*)(out1 + (size_t)ng * FHID + f2 * 2) = w;
        }
    } else {
        int wid = ((blockIdx.x - nbFast) * 256 + t) >> 6;
        int nw = (gridDim.x - nbFast) * 4;
        int u = lane >> 5, o = lane & 31;
        int fcnt = *nflag;
        for (int i = wid; i < fcnt; i += nw) {
            int n = flist[i];
            int d = deg[n];
            // root term: Wr1[d]^T x_n  (split-K across halves u)
            const float* Wr = Wr1 + (size_t)d * (FIN * FHID) + o;
            const float4* xr = (const float4*)(x + (size_t)n * FIN);
            float racc = 0.f;
            for (int c = u * 16; c < u * 16 + 16; ++c) {
                float4 xv = xr[c];
                racc += xv.x * Wr[(c * 4 + 0) * FHID] + xv.y * Wr[(c * 4 + 1) * FHID]
                      + xv.z * Wr[(c * 4 + 2) * FHID] + xv.w * Wr[(c * 4 + 3) * FHID];
            }
            racc += __shfl_xor(racc, 32);
            // neighbor aggregate: h = sum x_j  (feats lane*2, lane*2+1 per lane)
            int e1 = cursor[n];
            int e0 = e1 - d;
            float2 h = make_float2(0.f, 0.f);
            for (int k = e0; k < e1; ++k) {
                int s = adj[k];
                float2 v = *(const float2*)(x + (size_t)s * FIN + lane * 2);
                h.x += v.x; h.y += v.y;
            }
            // transform: W1[d]^T h  (split-K across halves u)
            const float* Wp = W1 + (size_t)d * (FIN * FHID) + o;
            float acc = 0.f;
            for (int f = u * 64; f < u * 64 + 64; ++f) {
                float hf = __shfl((f & 1) ? h.y : h.x, f >> 1);
                acc += hf * Wp[f * FHID];
            }
            acc += __shfl_xor(acc, 32);
            if (lane < 32) {
                float rv = racc + b1[d * FHID + o];
                out1[(size_t)n * FHID + o] = f2bf(fmaxf(acc + rv, 0.f));
            }
        }
    }
}

// ---------- layer2 gather (ALL nodes, 4 per wave): g[n] = sum_{j in N(n)} y_j  (f32) ----------
__global__ __launch_bounds__(256) void k_layer2g(const unsigned short* __restrict__ y,
                                                 const int* __restrict__ deg,
                                                 const int* __restrict__ cursor,
                                                 const int* __restrict__ adj,
                                                 float* __restrict__ g, int N) {
    int t = threadIdx.x;
    int lane = t & 63;
    int nb = blockIdx.x * 16 + (t >> 6) * 4;   // 4 nodes per wave
    if (nb >= N) return;
    int nl = min(nb + (lane & 3), N - 1);
    int dl = deg[nl];
    int cl = cursor[nl];
    int dg[4], e1v[4], e0v[4], cntv[4];
#pragma unroll
    for (int i = 0; i < 4; ++i) {
        dg[i] = __shfl(dl, i);
        e1v[i] = __shfl(cl, i);
        bool ok = (nb + i < N);
        cntv[i] = ok ? min(dg[i], 64) : 0;
        e0v[i] = e1v[i] - dg[i];
        if (!ok) e1v[i] = e0v[i];
    }
    float a0[4] = {0.f, 0.f, 0.f, 0.f};
    float a1[4] = {0.f, 0.f, 0.f, 0.f};
    gather16x4(y, adj, e0v, e1v, cntv, lane, a0, a1);
#pragma unroll
    for (int i = 0; i < 4; ++i) {
        a0[i] += __shfl_xor(a0[i], 16); a1[i] += __shfl_xor(a1[i], 16);
        a0[i] += __shfl_xor(a0[i], 32); a1[i] += __shfl_xor(a1[i], 32);
    }
    int gg = lane >> 4, f2 = lane & 15;
    int ng = nb + gg;
    if (ng < N) {
        float v0 = sel4(a0, gg), v1 = sel4(a1, gg);
        *(float2*)(g + (size_t)ng * FHID + f2 * 2) = make_float2(v0, v1);
    }
}

// ---------- post2 fused: fast blocks MFMA (skip flagged rows); tail blocks exact deg<10 fixup ----------
__global__ __launch_bounds__(256) void k_post2x(const float* __restrict__ g,
                                                const unsigned short* __restrict__ y,
                                                const unsigned short* __restrict__ wcat2,
                                                const float* __restrict__ b2,
                                                const int* __restrict__ deg,
                                                const int* __restrict__ cursor,
                                                const int* __restrict__ adj,
                                                const float* __restrict__ W2full,
                                                const float* __restrict__ Wr2full,
                                                const int* __restrict__ nflag,
                                                const int* __restrict__ flist,
                                                float* __restrict__ out,
                                                int N, int nbFast) {
    int t = threadIdx.x;
    if ((int)blockIdx.x < nbFast) {
        __shared__ __align__(16) unsigned short gt[64 * YPAD];
        __shared__ __align__(16) unsigned short yt[64 * YPAD];
        __shared__ __align__(16) unsigned short wt[128 * YPAD];
        __shared__ unsigned char flg[64];
        int row0 = blockIdx.x * 64;
        {   // stage wcat2 (4096 bf16 = 512 uint4): [128 n][32 k]
            const uint4* src = (const uint4*)wcat2;
#pragma unroll
            for (int i = 0; i < 2; ++i) {
                int idx = i * 256 + t;
                uint4 v = src[idx];
                int nn = idx >> 2;
                int k = (idx & 3) * 8;
                *(uint4*)(wt + nn * YPAD + k) = v;
            }
        }
        if (t < 64) {
            int rn = row0 + t;
            flg[t] = (rn < N) ? (unsigned char)(deg[rn] < MAXDEG) : (unsigned char)1;
        }
        {   // stage g rows (f32 -> bf16) and y rows (bf16)
            int r = t >> 2, c0 = (t & 3) * 8;
            int rn = min(row0 + r, N - 1);
            const float4* gs = (const float4*)(g + (size_t)rn * FHID + c0);
            float4 v0 = gs[0], v1 = gs[1];
            ushort4 p0, p1;
            p0.x = f2bf(v0.x); p0.y = f2bf(v0.y); p0.z = f2bf(v0.z); p0.w = f2bf(v0.w);
            p1.x = f2bf(v1.x); p1.y = f2bf(v1.y); p1.z = f2bf(v1.z); p1.w = f2bf(v1.w);
            *(ushort4*)(gt + r * YPAD + c0) = p0;
            *(ushort4*)(gt + r * YPAD + c0 + 4) = p1;
            uint4 vy = *(const uint4*)(y + (size_t)rn * FHID + c0);
            *(uint4*)(yt + r * YPAD + c0) = vy;
        }
        __syncthreads();
        int w = t >> 6, lane = t & 63;
        int m = lane & 15, quad = lane >> 4;
        short8 ag = *(const short8*)(gt + (w * 16 + m) * YPAD + quad * 8);
        short8 ay = *(const short8*)(yt + (w * 16 + m) * YPAD + quad * 8);
        int rbase = w * 16 + quad * 4;   // block-local row
#pragma unroll
        for (int ct = 0; ct < 4; ++ct) {
            short8 bw = *(const short8*)(wt + (ct * 16 + m) * YPAD + quad * 8);
            short8 br = *(const short8*)(wt + ((64 + ct * 16) + m) * YPAD + quad * 8);
            f32x4 acc = (f32x4){0.f, 0.f, 0.f, 0.f};
            acc = __builtin_amdgcn_mfma_f32_16x16x32_bf16(ag, bw, acc, 0, 0, 0);
            acc = __builtin_amdgcn_mfma_f32_16x16x32_bf16(ay, br, acc, 0, 0, 0);
            int o = ct * 16 + m;
            float bias = b2[MAXDEG * FOUT + o];
#pragma unroll
            for (int rg = 0; rg < 4; ++rg) {
                int rl = rbase + rg;
                int nn = row0 + rl;
                if (nn < N && !flg[rl]) out[(size_t)nn * FOUT + o] = acc[rg] + bias;
            }
        }
    } else {
        int wid = ((blockIdx.x - nbFast) * 256 + t) >> 6;
        int nw = (gridDim.x - nbFast) * 4;
        int lane = t & 63;
        int fcnt = *nflag;
        for (int i = wid; i < fcnt; i += nw) {
            int n = flist[i];
            int d = deg[n];
            float a0 = 0.f, a1 = 0.f;
            if (d > 0) {
                int e1 = cursor[n];
                gather16(y, adj, e1 - d, e1, d, lane, a0, a1);
                a0 += __shfl_xor(a0, 16); a1 += __shfl_xor(a1, 16);
                a0 += __shfl_xor(a0, 32); a1 += __shfl_xor(a1, 32);
            }
            const float* W2p  = W2full  + (size_t)d * (FHID * FOUT) + lane;
            const float* Wr2p = Wr2full + (size_t)d * (FHID * FOUT) + lane;
            unsigned int yw = *(const unsigned int*)(y + (size_t)n * FHID + (lane & 15) * 2);
            float acc = b2[d * FOUT + lane];
#pragma unroll
            for (int q = 0; q < 16; ++q) {
                float g0 = __shfl(a0, q);
                float g1 = __shfl(a1, q);
                unsigned int yq = __shfl(yw, q);
                acc += g0 * W2p[(2 * q) * FOUT] + g1 * W2p[(2 * q + 1) * FOUT]
                     + bflo(yq) * Wr2p[(2 * q) * FOUT] + bfhi(yq) * Wr2p[(2 * q + 1) * FOUT];
            }
            out[(size_t)n * FOUT + lane] = acc;
        }
    }
}

extern "C" void kernel_launch(void* const* d_in, const int* in_sizes, int n_in,
                              void* d_out, int out_size, void* d_ws, size_t ws_size,
                              hipStream_t stream) {
    const float* x   = (const float*)d_in[0];
    const int*   ei  = (const int*)d_in[1];   // int32, [2, E] flat
    const float* W1  = (const float*)d_in[2];
    const float* b1  = (const float*)d_in[3];
    const float* Wr1 = (const float*)d_in[4];
    const float* W2  = (const float*)d_in[5];
    const float* b2  = (const float*)d_in[6];
    const float* Wr2 = (const float*)d_in[7];

    int N = in_sizes[0] / FIN;
    int E = in_sizes[1] / 2;
    int K  = (N + 255) >> BSH;   // dst buckets

    char* ws = (char*)d_ws;
    size_t off = 0;
    auto alloc = [&](size_t bytes) {
        void* ptr = ws + off;
        off += (bytes + 511) / 512 * 512;
        return ptr;
    };
    int* deg              = (int*)alloc((size_t)N * sizeof(int));
    int* cursor           = (int*)alloc((size_t)N * sizeof(int));
    int* bcnt             = (int*)alloc((size_t)(K + 1) * sizeof(int));  // +1: nflag counter
    int* nflag            = bcnt + K;
    int* bstart           = (int*)alloc((size_t)K * sizeof(int));
    int* gcur             = (int*)alloc((size_t)K * sizeof(int));
    int* flist            = (int*)alloc((size_t)N * sizeof(int));
    int* adj              = (int*)alloc((size_t)E * sizeof(int));
    unsigned short* z10   = (unsigned short*)alloc((size_t)N * FHID * 2);
    unsigned short* r1    = (unsigned short*)alloc((size_t)N * FHID * 2);
    unsigned short* out1  = (unsigned short*)alloc((size_t)N * FHID * 2);
    // packed pairs (E*4B) and g (N*FHID*4B) share one region: pairs dead after k_passB2,
    // g first written by k_layer2g which runs later.
    size_t pairsB = (size_t)E * sizeof(unsigned int);
    size_t gB     = (size_t)N * FHID * sizeof(float);
    void* shared_region   = alloc(pairsB > gB ? pairsB : gB);
    float* g              = (float*)shared_region;
    unsigned int* pairs   = (unsigned int*)shared_region;
    unsigned short* wcat1 = (unsigned short*)alloc(64 * 128 * 2);
    unsigned short* wcat2 = (unsigned short*)alloc(128 * 32 * 2);

    float* out = (float*)d_out;

    (void)hipMemsetAsync(bcnt, 0, (size_t)(K + 1) * sizeof(int), stream);

    int nwgA = (E + ACHUNK - 1) / ACHUNK;
    k_bhistp<<<nwgA, 256, 0, stream>>>(ei, E, N, bcnt, W1, Wr1, W2, Wr2, wcat1, wcat2);
    k_scanb<<<1, 1024, 0, stream>>>(bcnt, K, bstart, gcur);
    k_passA<<<nwgA, 256, 0, stream>>>(ei, E, N, gcur, pairs);
    k_passB2<<<K, 256, 0, stream>>>(pairs, bstart, gcur, deg, cursor, adj, nflag, flist, N);

    int nb64 = (N + 63) / 64;     // MFMA kernels: 64 nodes per block
    int nb_quad = (N + 15) / 16;  // gather kernels: 4 nodes per wave, 4 waves per block
    const int FIXB = 512;         // fixup tail blocks (wave-per-flagged-node, grid-stride)

    k_pre1m<<<nb64, 256, 0, stream>>>(x, wcat1, b1, z10, r1, N);
    k_layer1x<<<nb_quad + FIXB, 256, 0, stream>>>(z10, r1, deg, cursor, adj,
                                                  x, W1, b1, Wr1, nflag, flist, out1,
                                                  N, nb_quad);
    k_layer2g<<<nb_quad, 256, 0, stream>>>(out1, deg, cursor, adj, g, N);
    k_post2x<<<nb64 + FIXB, 256, 0, stream>>>(g, out1, wcat2, b2, deg, cursor, adj,
                                              W2, Wr2, nflag, flist, out, N, nb64);
}

// Round 10
// 269.418 us; speedup vs baseline: 1.0633x; 1.0633x over previous
//
#include <hip/hip_runtime.h>

#define FIN 128
#define FHID 32
#define FOUT 64
#define MAXDEG 10
#define BSH 8              // dst bucket = dst >> 8 (256 dsts per bucket)
#define ACHUNK 4096        // edges per pass-A workgroup (16 per thread)
#define XPAD 136           // LDS row stride (bf16) for 128-k tiles
#define YPAD 40            // LDS row stride (bf16) for 32-k tiles: 80B, 16B-aligned
#define SRCBITS 20         // packed pair: src in bits 0..19 (requires N < 2^20), dst&255 in 20..27

typedef __attribute__((ext_vector_type(8))) short short8;
typedef __attribute__((ext_vector_type(4))) float f32x4;

// edge_index arrives as int32: layout [2, E] flat: src = ei[e], dst = ei[E + e].

__device__ __forceinline__ float bf2f(unsigned short u) {
    union { unsigned int i; float f; } c; c.i = ((unsigned int)u) << 16; return c.f;
}
__device__ __forceinline__ unsigned short f2bf(float f) {
    union { float f; unsigned int i; } c; c.f = f;
    unsigned int r = c.i + 0x7FFF + ((c.i >> 16) & 1);   // round-nearest-even
    return (unsigned short)(r >> 16);
}
__device__ __forceinline__ float bflo(unsigned int w) { return bf2f((unsigned short)(w & 0xffff)); }
__device__ __forceinline__ float bfhi(unsigned int w) { return bf2f((unsigned short)(w >> 16)); }
__device__ __forceinline__ unsigned int pk2(float lo, float hi) {
    return (unsigned int)f2bf(lo) | ((unsigned int)f2bf(hi) << 16);
}

// ---------- CSR build (bucket-hierarchical: NO per-edge global atomics) ----------

// Per-block LDS histogram over dst buckets; one global atomic per (block, bucket).
// Block 0 additionally prepacks the bucket-10 weights (hidden under other blocks).
__global__ __launch_bounds__(256) void k_bhistp(const int* __restrict__ ei, int E, int N,
                                                int* __restrict__ bcnt,
                                                const float* __restrict__ W1,
                                                const float* __restrict__ Wr1,
                                                const float* __restrict__ W2,
                                                const float* __restrict__ Wr2,
                                                unsigned short* __restrict__ wcat1,
                                                unsigned short* __restrict__ wcat2) {
    __shared__ int hist[1024];
    int K = ((N + 255) >> BSH);
    int t = threadIdx.x;
    long long cb = (long long)blockIdx.x * ACHUNK;
    for (int i = t; i < K; i += 256) hist[i] = 0;
    __syncthreads();
#pragma unroll
    for (int i = 0; i < 16; ++i) {
        long long e = cb + t + (long long)i * 256;
        if (e < E) {
            int ss = ei[e];
            int dd = ei[E + e];
            if ((unsigned)ss < (unsigned)N && (unsigned)dd < (unsigned)N)
                atomicAdd(&hist[dd >> BSH], 1);
        }
    }
    __syncthreads();
    for (int i = t; i < K; i += 256) {
        int h = hist[i];
        if (h) atomicAdd(&bcnt[i], h);
    }
    if (blockIdx.x == 0) {   // prepack: wcat1 [64n][128k], wcat2 [128n][32k]
        const float* W1b  = W1  + (size_t)MAXDEG * FIN * FHID;
        const float* Wr1b = Wr1 + (size_t)MAXDEG * FIN * FHID;
        const float* W2b  = W2  + (size_t)MAXDEG * FHID * FOUT;
        const float* Wr2b = Wr2 + (size_t)MAXDEG * FHID * FOUT;
        for (int i = 0; i < 32; ++i) {
            int idx = i * 256 + t;            // 8192
            int n = idx >> 7, k = idx & 127;
            float v = (n < 32) ? W1b[k * FHID + n] : Wr1b[k * FHID + (n - 32)];
            wcat1[idx] = f2bf(v);
        }
        for (int i = 0; i < 16; ++i) {
            int idx = i * 256 + t;            // 4096
            int n = idx >> 5, k = idx & 31;
            float v = (n < 64) ? W2b[k * FOUT + n] : Wr2b[k * FOUT + (n - 64)];
            wcat2[idx] = f2bf(v);
        }
    }
}

// Single-block exclusive scan of bcnt[0..K) -> bstart, gcur  (requires K <= 1024).
__global__ __launch_bounds__(1024) void k_scanb(const int* __restrict__ bcnt, int K,
                                                int* __restrict__ bstart,
                                                int* __restrict__ gcur) {
    __shared__ int tmp[1024];
    int t = threadIdx.x;
    int v = (t < K) ? bcnt[t] : 0;
    tmp[t] = v;
    __syncthreads();
    for (int off = 1; off < 1024; off <<= 1) {
        int a = (t >= off) ? tmp[t - off] : 0;
        __syncthreads();
        tmp[t] += a;
        __syncthreads();
    }
    if (t < K) { int s = tmp[t] - v; bstart[t] = s; gcur[t] = s; }
}

// Pass A: bucket edges by dst>>8 into packed pairs[], line-coalesced appends.
__global__ __launch_bounds__(256) void k_passA(const int* __restrict__ ei, int E, int N,
                                               int* __restrict__ gcur,
                                               unsigned int* __restrict__ pairs) {
    __shared__ int hist[1024];
    __shared__ int base[1024];
    int K = ((N + 255) >> BSH);
    int t = threadIdx.x;
    long long cb = (long long)blockIdx.x * ACHUNK;
    for (int i = t; i < K; i += 256) hist[i] = 0;
    __syncthreads();
    int sv[16], dv[16];
#pragma unroll
    for (int i = 0; i < 16; ++i) {
        sv[i] = -1; dv[i] = 0;
        long long e = cb + t + (long long)i * 256;
        if (e < E) {
            int ss = ei[e];
            int dd = ei[E + e];
            if ((unsigned)ss < (unsigned)N && (unsigned)dd < (unsigned)N) {
                sv[i] = ss; dv[i] = dd;
            }
        }
    }
#pragma unroll
    for (int i = 0; i < 16; ++i)
        if (sv[i] >= 0) atomicAdd(&hist[dv[i] >> BSH], 1);
    __syncthreads();
    for (int i = t; i < K; i += 256) {
        int h = hist[i];
        base[i] = h ? atomicAdd(&gcur[i], h) : 0;
    }
    __syncthreads();
    for (int i = t; i < K; i += 256) hist[i] = 0;
    __syncthreads();
#pragma unroll
    for (int i = 0; i < 16; ++i) {
        if (sv[i] >= 0) {
            int b = dv[i] >> BSH;
            int off = atomicAdd(&hist[b], 1);
            pairs[base[b] + off] = (unsigned int)sv[i] | ((unsigned int)(dv[i] & 255) << SRCBITS);
        }
    }
}

// Pass B2: per bucket -- derive per-node degrees in LDS (no global atomics),
// in-LDS exclusive scan -> row starts, write deg/cursor, scatter pairs->adj,
// and append deg<MAXDEG node ids to the compact flagged list.
__global__ __launch_bounds__(256) void k_passB2(const unsigned int* __restrict__ pairs,
                                                const int* __restrict__ bstart,
                                                const int* __restrict__ gcur,
                                                int* __restrict__ deg,
                                                int* __restrict__ cursor,
                                                int* __restrict__ adj,
                                                int* __restrict__ nflag,
                                                int* __restrict__ flist, int N) {
    __shared__ int cnt[256];
    __shared__ int scn[256];
    __shared__ int cur[256];
    __shared__ int fids[256];
    __shared__ int fcnt, fbase;
    int b = blockIdx.x;
    int lo = b << BSH;
    int t = threadIdx.x;
    int nvalid = min(256, N - lo);
    cnt[t] = 0;
    if (t == 0) fcnt = 0;
    int pstart = bstart[b];
    int pend = gcur[b];
    __syncthreads();
    for (int i = pstart + t; i < pend; i += 256)
        atomicAdd(&cnt[pairs[i] >> SRCBITS], 1);
    __syncthreads();
    int v = cnt[t];
    scn[t] = v;
    __syncthreads();
    for (int off = 1; off < 256; off <<= 1) {
        int a = (t >= off) ? scn[t - off] : 0;
        __syncthreads();
        scn[t] += a;
        __syncthreads();
    }
    int rowstart = pstart + scn[t] - v;
    cur[t] = rowstart;
    if (t < nvalid) {
        deg[lo + t] = v;
        cursor[lo + t] = rowstart + v;    // cursor = row END
        if (v < MAXDEG) { int p = atomicAdd(&fcnt, 1); fids[p] = lo + t; }
    }
    __syncthreads();
    if (t == 0 && fcnt > 0) fbase = atomicAdd(nflag, fcnt);
    __syncthreads();
    if (t < fcnt) flist[fbase + t] = fids[t];
    for (int i = pstart + t; i < pend; i += 256) {
        unsigned int pr = pairs[i];
        int pos = atomicAdd(&cur[pr >> SRCBITS], 1);
        adj[pos] = (int)(pr & ((1u << SRCBITS) - 1));
    }
}

// ---------- pre1 (MFMA): [z10 | r1] = x @ [W1[10] | Wr1[10]] + [0 | b1[10]] ----------
__global__ __launch_bounds__(256) void k_pre1m(const float* __restrict__ x,
                                               const unsigned short* __restrict__ wcat1,
                                               const float* __restrict__ b1,
                                               unsigned short* __restrict__ z10,
                                               unsigned short* __restrict__ r1, int N) {
    __shared__ __align__(16) unsigned short xt[64 * XPAD];
    __shared__ __align__(16) unsigned short wt[64 * XPAD];
    int t = threadIdx.x;
    int row0 = blockIdx.x * 64;
    {   // stage Wcat1 (8192 bf16 = 1024 uint4)
        const uint4* src = (const uint4*)wcat1;
#pragma unroll
        for (int i = 0; i < 4; ++i) {
            int idx = i * 256 + t;
            uint4 v = src[idx];
            int n = idx >> 4;
            int k = (idx & 15) * 8;
            *(uint4*)(wt + n * XPAD + k) = v;
        }
    }
    {   // stage x rows -> bf16
        int r = t >> 2;
        int c0 = (t & 3) * 32;
        int cr = min(row0 + r, N - 1);
        const float4* xs = (const float4*)(x + (size_t)cr * FIN + c0);
        unsigned short* dst = xt + r * XPAD + c0;
#pragma unroll
        for (int i = 0; i < 8; ++i) {
            float4 v = xs[i];
            ushort4 b;
            b.x = f2bf(v.x); b.y = f2bf(v.y); b.z = f2bf(v.z); b.w = f2bf(v.w);
            *(ushort4*)(dst + i * 4) = b;
        }
    }
    __syncthreads();
    int w = t >> 6, lane = t & 63;
    int m = lane & 15, quad = lane >> 4;
    const unsigned short* arow = xt + (w * 16 + m) * XPAD + quad * 8;
    short8 af[4];
#pragma unroll
    for (int kt = 0; kt < 4; ++kt) af[kt] = *(const short8*)(arow + kt * 32);
    f32x4 acc[4];
#pragma unroll
    for (int ct = 0; ct < 4; ++ct) acc[ct] = (f32x4){0.f, 0.f, 0.f, 0.f};
#pragma unroll
    for (int ct = 0; ct < 4; ++ct) {
        const unsigned short* brow = wt + (ct * 16 + m) * XPAD + quad * 8;
#pragma unroll
        for (int kt = 0; kt < 4; ++kt) {
            short8 bfr = *(const short8*)(brow + kt * 32);
            acc[ct] = __builtin_amdgcn_mfma_f32_16x16x32_bf16(af[kt], bfr, acc[ct], 0, 0, 0);
        }
    }
    int rbase = row0 + w * 16 + quad * 4;
#pragma unroll
    for (int ct = 0; ct < 4; ++ct) {
        float bias = (ct >= 2) ? b1[MAXDEG * FHID + (ct - 2) * 16 + m] : 0.f;
#pragma unroll
        for (int rg = 0; rg < 4; ++rg) {
            int n = rbase + rg;
            if (n < N) {
                float v = acc[ct][rg];
                if (ct < 2) z10[(size_t)n * FHID + ct * 16 + m] = f2bf(v);
                else        r1[(size_t)n * FHID + (ct - 2) * 16 + m] = f2bf(v + bias);
            }
        }
    }
}

// ---------- single-node 16-lane/edge gather (fixup paths) ----------
__device__ __forceinline__ void gather16(const unsigned short* __restrict__ rows,
                                         const int* __restrict__ adj,
                                         int e0, int e1, int cnt, int lane,
                                         float& a0, float& a1) {
    int e = lane >> 4, f2 = lane & 15;
    int sidx = adj[min(e0 + lane, e1 - 1)];
    const unsigned short* rb = rows + f2 * 2;
    int nfull = cnt >> 4;
    for (int c = 0; c < nfull; ++c) {
        int i0 = c * 16 + e;
        int s0 = __shfl(sidx, i0);
        int s1 = __shfl(sidx, i0 + 4);
        int s2 = __shfl(sidx, i0 + 8);
        int s3 = __shfl(sidx, i0 + 12);
        unsigned int w0 = *(const unsigned int*)(rb + (size_t)s0 * FHID);
        unsigned int w1 = *(const unsigned int*)(rb + (size_t)s1 * FHID);
        unsigned int w2 = *(const unsigned int*)(rb + (size_t)s2 * FHID);
        unsigned int w3 = *(const unsigned int*)(rb + (size_t)s3 * FHID);
        a0 += bflo(w0); a1 += bfhi(w0);
        a0 += bflo(w1); a1 += bfhi(w1);
        a0 += bflo(w2); a1 += bfhi(w2);
        a0 += bflo(w3); a1 += bfhi(w3);
    }
    if (cnt & 15) {
        int i0 = nfull * 16 + e;
        int i1 = i0 + 4, i2 = i0 + 8, i3 = i0 + 12;
        int s0 = __shfl(sidx, min(i0, cnt - 1));
        int s1 = __shfl(sidx, min(i1, cnt - 1));
        int s2 = __shfl(sidx, min(i2, cnt - 1));
        int s3 = __shfl(sidx, min(i3, cnt - 1));
        unsigned int w0 = *(const unsigned int*)(rb + (size_t)s0 * FHID);
        unsigned int w1 = *(const unsigned int*)(rb + (size_t)s1 * FHID);
        unsigned int w2 = *(const unsigned int*)(rb + (size_t)s2 * FHID);
        unsigned int w3 = *(const unsigned int*)(rb + (size_t)s3 * FHID);
        float c0 = (i0 < cnt) ? 1.f : 0.f;
        float c1 = (i1 < cnt) ? 1.f : 0.f;
        float c2 = (i2 < cnt) ? 1.f : 0.f;
        float c3 = (i3 < cnt) ? 1.f : 0.f;
        a0 = fmaf(c0, bflo(w0), a0); a1 = fmaf(c0, bfhi(w0), a1);
        a0 = fmaf(c1, bflo(w1), a0); a1 = fmaf(c1, bfhi(w1), a1);
        a0 = fmaf(c2, bflo(w2), a0); a1 = fmaf(c2, bfhi(w2), a1);
        a0 = fmaf(c3, bflo(w3), a0); a1 = fmaf(c3, bfhi(w3), a1);
    }
    for (int k = e0 + 64 + e; k < e1; k += 4) {    // rare tail (deg>64)
        int s = adj[k];
        unsigned int w = *(const unsigned int*)(rb + (size_t)s * FHID);
        a0 += bflo(w); a1 += bfhi(w);
    }
}

// ---------- 2-node interleaved gather: 8 loads in flight per chunk ----------
// Node A: accumulate into a0,a1; node B into b0,b1. cntX==0 disables node X (loads
// degenerate to a single broadcast address, contributions masked to 0).
__device__ __forceinline__ void gather16x2(const unsigned short* __restrict__ rows,
                                           const int* __restrict__ adj,
                                           int e0a, int e1a, int cntA,
                                           int e0b, int e1b, int cntB, int lane,
                                           float& a0, float& a1, float& b0, float& b1) {
    int e = lane >> 4, f2 = lane & 15;
    const unsigned short* rb = rows + f2 * 2;
    int cA = max(cntA - 1, 0);
    int cB = max(cntB - 1, 0);
    int sA = adj[e0a + min(lane, cA)];
    int sB = adj[e0b + min(lane, cB)];
    int nch = (max(cntA, cntB) + 15) >> 4;
    for (int c = 0; c < nch; ++c) {
        int i0 = c * 16 + e;
        int i1 = i0 + 4, i2 = i0 + 8, i3 = i0 + 12;
        int as0 = __shfl(sA, min(i0, cA));
        int as1 = __shfl(sA, min(i1, cA));
        int as2 = __shfl(sA, min(i2, cA));
        int as3 = __shfl(sA, min(i3, cA));
        int bs0 = __shfl(sB, min(i0, cB));
        int bs1 = __shfl(sB, min(i1, cB));
        int bs2 = __shfl(sB, min(i2, cB));
        int bs3 = __shfl(sB, min(i3, cB));
        unsigned int aw0 = *(const unsigned int*)(rb + (size_t)as0 * FHID);
        unsigned int aw1 = *(const unsigned int*)(rb + (size_t)as1 * FHID);
        unsigned int aw2 = *(const unsigned int*)(rb + (size_t)as2 * FHID);
        unsigned int aw3 = *(const unsigned int*)(rb + (size_t)as3 * FHID);
        unsigned int bw0 = *(const unsigned int*)(rb + (size_t)bs0 * FHID);
        unsigned int bw1 = *(const unsigned int*)(rb + (size_t)bs1 * FHID);
        unsigned int bw2 = *(const unsigned int*)(rb + (size_t)bs2 * FHID);
        unsigned int bw3 = *(const unsigned int*)(rb + (size_t)bs3 * FHID);
        float ac0 = (i0 < cntA) ? 1.f : 0.f;
        float ac1 = (i1 < cntA) ? 1.f : 0.f;
        float ac2 = (i2 < cntA) ? 1.f : 0.f;
        float ac3 = (i3 < cntA) ? 1.f : 0.f;
        float bc0 = (i0 < cntB) ? 1.f : 0.f;
        float bc1 = (i1 < cntB) ? 1.f : 0.f;
        float bc2 = (i2 < cntB) ? 1.f : 0.f;
        float bc3 = (i3 < cntB) ? 1.f : 0.f;
        a0 = fmaf(ac0, bflo(aw0), a0); a1 = fmaf(ac0, bfhi(aw0), a1);
        a0 = fmaf(ac1, bflo(aw1), a0); a1 = fmaf(ac1, bfhi(aw1), a1);
        a0 = fmaf(ac2, bflo(aw2), a0); a1 = fmaf(ac2, bfhi(aw2), a1);
        a0 = fmaf(ac3, bflo(aw3), a0); a1 = fmaf(ac3, bfhi(aw3), a1);
        b0 = fmaf(bc0, bflo(bw0), b0); b1 = fmaf(bc0, bfhi(bw0), b1);
        b0 = fmaf(bc1, bflo(bw1), b0); b1 = fmaf(bc1, bfhi(bw1), b1);
        b0 = fmaf(bc2, bflo(bw2), b0); b1 = fmaf(bc2, bfhi(bw2), b1);
        b0 = fmaf(bc3, bflo(bw3), b0); b1 = fmaf(bc3, bfhi(bw3), b1);
    }
    for (int k = e0a + 64 + e; k < e1a; k += 4) {    // rare tail (deg>64)
        int s = adj[k];
        unsigned int w = *(const unsigned int*)(rb + (size_t)s * FHID);
        a0 += bflo(w); a1 += bfhi(w);
    }
    for (int k = e0b + 64 + e; k < e1b; k += 4) {
        int s = adj[k];
        unsigned int w = *(const unsigned int*)(rb + (size_t)s * FHID);
        b0 += bflo(w); b1 += bfhi(w);
    }
}

// ---------- layer1 fused: fast blocks gather z10 (2 nodes/wave); tail blocks deg<10 fixup ----------
__global__ __launch_bounds__(256) void k_layer1x(const unsigned short* __restrict__ z10,
                                                 const unsigned short* __restrict__ r1,
                                                 const int* __restrict__ deg,
                                                 const int* __restrict__ cursor,
                                                 const int* __restrict__ adj,
                                                 const float* __restrict__ x,
                                                 const float* __restrict__ W1,
                                                 const float* __restrict__ b1,
                                                 const float* __restrict__ Wr1,
                                                 const int* __restrict__ nflag,
                                                 const int* __restrict__ flist,
                                                 unsigned short* __restrict__ out1,
                                                 int N, int nbFast) {
    int t = threadIdx.x;
    int lane = t & 63;
    if ((int)blockIdx.x < nbFast) {
        int n0 = blockIdx.x * 8 + (t >> 6) * 2;
        int n1 = n0 + 1;
        bool ok0 = (n0 < N), ok1 = (n1 < N);
        int dg0 = ok0 ? deg[n0] : 0;
        int dg1 = ok1 ? deg[n1] : 0;
        ok0 = ok0 && (dg0 >= MAXDEG);          // deg<10 handled by fix blocks
        ok1 = ok1 && (dg1 >= MAXDEG);
        if (!ok0 && !ok1) return;
        int e1a = ok0 ? cursor[n0] : 0;
        int e1b = ok1 ? cursor[n1] : 0;
        int e0a = e1a - (ok0 ? dg0 : 0);
        int e0b = e1b - (ok1 ? dg1 : 0);
        int cntA = ok0 ? min(dg0, 64) : 0;
        int cntB = ok1 ? min(dg1, 64) : 0;
        float a0 = 0.f, a1 = 0.f, b0 = 0.f, b1 = 0.f;
        gather16x2(z10, adj, e0a, e1a, cntA, e0b, e1b, cntB, lane, a0, a1, b0, b1);
        a0 += __shfl_xor(a0, 16); a1 += __shfl_xor(a1, 16);
        a0 += __shfl_xor(a0, 32); a1 += __shfl_xor(a1, 32);
        b0 += __shfl_xor(b0, 16); b1 += __shfl_xor(b1, 16);
        b0 += __shfl_xor(b0, 32); b1 += __shfl_xor(b1, 32);
        if (ok0 && lane < 16) {
            unsigned int rv = *(const unsigned int*)(r1 + (size_t)n0 * FHID + lane * 2);
            unsigned int w = pk2(fmaxf(a0 + bflo(rv), 0.f), fmaxf(a1 + bfhi(rv), 0.f));
            *(unsigned int*)(out1 + (size_t)n0 * FHID + lane * 2) = w;
        }
        if (ok1 && lane < 16) {
            unsigned int rv = *(const unsigned int*)(r1 + (size_t)n1 * FHID + lane * 2);
            unsigned int w = pk2(fmaxf(b0 + bflo(rv), 0.f), fmaxf(b1 + bfhi(rv), 0.f));
            *(unsigned int*)(out1 + (size_t)n1 * FHID + lane * 2) = w;
        }
    } else {
        int wid = ((blockIdx.x - nbFast) * 256 + t) >> 6;
        int nw = (gridDim.x - nbFast) * 4;
        int u = lane >> 5, o = lane & 31;
        int fcnt = *nflag;
        for (int i = wid; i < fcnt; i += nw) {
            int n = flist[i];
            int d = deg[n];
            // root term: Wr1[d]^T x_n  (split-K across halves u)
            const float* Wr = Wr1 + (size_t)d * (FIN * FHID) + o;
            const float4* xr = (const float4*)(x + (size_t)n * FIN);
            float racc = 0.f;
            for (int c = u * 16; c < u * 16 + 16; ++c) {
                float4 xv = xr[c];
                racc += xv.x * Wr[(c * 4 + 0) * FHID] + xv.y * Wr[(c * 4 + 1) * FHID]
                      + xv.z * Wr[(c * 4 + 2) * FHID] + xv.w * Wr[(c * 4 + 3) * FHID];
            }
            racc += __shfl_xor(racc, 32);
            // neighbor aggregate: h = sum x_j  (feats lane*2, lane*2+1 per lane)
            int e1 = cursor[n];
            int e0 = e1 - d;
            float2 h = make_float2(0.f, 0.f);
            for (int k = e0; k < e1; ++k) {
                int s = adj[k];
                float2 v = *(const float2*)(x + (size_t)s * FIN + lane * 2);
                h.x += v.x; h.y += v.y;
            }
            // transform: W1[d]^T h  (split-K across halves u)
            const float* Wp = W1 + (size_t)d * (FIN * FHID) + o;
            float acc = 0.f;
            for (int f = u * 64; f < u * 64 + 64; ++f) {
                float hf = __shfl((f & 1) ? h.y : h.x, f >> 1);
                acc += hf * Wp[f * FHID];
            }
            acc += __shfl_xor(acc, 32);
            if (lane < 32) {
                float rv = racc + b1[d * FHID + o];
                out1[(size_t)n * FHID + o] = f2bf(fmaxf(acc + rv, 0.f));
            }
        }
    }
}

// ---------- layer2 gather (ALL nodes, 2 per wave): g[n] = sum_{j in N(n)} y_j  (f32) ----------
__global__ __launch_bounds__(256) void k_layer2g(const unsigned short* __restrict__ y,
                                                 const int* __restrict__ deg,
                                                 const int* __restrict__ cursor,
                                                 const int* __restrict__ adj,
                                                 float* __restrict__ g, int N) {
    int t = threadIdx.x;
    int lane = t & 63;
    int n0 = blockIdx.x * 8 + (t >> 6) * 2;
    int n1 = n0 + 1;
    bool ok0 = (n0 < N), ok1 = (n1 < N);
    if (!ok0) return;
    int dg0 = deg[n0];
    int dg1 = ok1 ? deg[n1] : 0;
    int e1a = cursor[n0];
    int e1b = ok1 ? cursor[n1] : 0;
    int e0a = e1a - dg0;
    int e0b = e1b - dg1;
    int cntA = min(dg0, 64);
    int cntB = ok1 ? min(dg1, 64) : 0;
    float a0 = 0.f, a1 = 0.f, b0 = 0.f, b1 = 0.f;
    gather16x2(y, adj, e0a, e1a, cntA, e0b, e1b, cntB, lane, a0, a1, b0, b1);
    a0 += __shfl_xor(a0, 16); a1 += __shfl_xor(a1, 16);
    a0 += __shfl_xor(a0, 32); a1 += __shfl_xor(a1, 32);
    b0 += __shfl_xor(b0, 16); b1 += __shfl_xor(b1, 16);
    b0 += __shfl_xor(b0, 32); b1 += __shfl_xor(b1, 32);
    if (lane < 16) {
        *(float2*)(g + (size_t)n0 * FHID + lane * 2) = make_float2(a0, a1);
        if (ok1) *(float2*)(g + (size_t)n1 * FHID + lane * 2) = make_float2(b0, b1);
    }
}

// ---------- post2 fused: fast blocks MFMA (skip flagged rows); tail blocks exact deg<10 fixup ----------
__global__ __launch_bounds__(256) void k_post2x(const float* __restrict__ g,
                                                const unsigned short* __restrict__ y,
                                                const unsigned short* __restrict__ wcat2,
                                                const float* __restrict__ b2,
                                                const int* __restrict__ deg,
                                                const int* __restrict__ cursor,
                                                const int* __restrict__ adj,
                                                const float* __restrict__ W2full,
                                                const float* __restrict__ Wr2full,
                                                const int* __restrict__ nflag,
                                                const int* __restrict__ flist,
                                                float* __restrict__ out,
                                                int N, int nbFast) {
    int t = threadIdx.x;
    if ((int)blockIdx.x < nbFast) {
        __shared__ __align__(16) unsigned short gt[64 * YPAD];
        __shared__ __align__(16) unsigned short yt[64 * YPAD];
        __shared__ __align__(16) unsigned short wt[128 * YPAD];
        __shared__ unsigned char flg[64];
        int row0 = blockIdx.x * 64;
        {   // stage wcat2 (4096 bf16 = 512 uint4): [128 n][32 k]
            const uint4* src = (const uint4*)wcat2;
#pragma unroll
            for (int i = 0; i < 2; ++i) {
                int idx = i * 256 + t;
                uint4 v = src[idx];
                int nn = idx >> 2;
                int k = (idx & 3) * 8;
                *(uint4*)(wt + nn * YPAD + k) = v;
            }
        }
        if (t < 64) {
            int rn = row0 + t;
            flg[t] = (rn < N) ? (unsigned char)(deg[rn] < MAXDEG) : (unsigned char)1;
        }
        {   // stage g rows (f32 -> bf16) and y rows (bf16)
            int r = t >> 2, c0 = (t & 3) * 8;
            int rn = min(row0 + r, N - 1);
            const float4* gs = (const float4*)(g + (size_t)rn * FHID + c0);
            float4 v0 = gs[0], v1 = gs[1];
            ushort4 p0, p1;
            p0.x = f2bf(v0.x); p0.y = f2bf(v0.y); p0.z = f2bf(v0.z); p0.w = f2bf(v0.w);
            p1.x = f2bf(v1.x); p1.y = f2bf(v1.y); p1.z = f2bf(v1.z); p1.w = f2bf(v1.w);
            *(ushort4*)(gt + r * YPAD + c0) = p0;
            *(ushort4*)(gt + r * YPAD + c0 + 4) = p1;
            uint4 vy = *(const uint4*)(y + (size_t)rn * FHID + c0);
            *(uint4*)(yt + r * YPAD + c0) = vy;
        }
        __syncthreads();
        int w = t >> 6, lane = t & 63;
        int m = lane & 15, quad = lane >> 4;
        short8 ag = *(const short8*)(gt + (w * 16 + m) * YPAD + quad * 8);
        short8 ay = *(const short8*)(yt + (w * 16 + m) * YPAD + quad * 8);
        int rbase = w * 16 + quad * 4;   // block-local row
#pragma unroll
        for (int ct = 0; ct < 4; ++ct) {
            short8 bw = *(const short8*)(wt + (ct * 16 + m) * YPAD + quad * 8);
            short8 br = *(const short8*)(wt + ((64 + ct * 16) + m) * YPAD + quad * 8);
            f32x4 acc = (f32x4){0.f, 0.f, 0.f, 0.f};
            acc = __builtin_amdgcn_mfma_f32_16x16x32_bf16(ag, bw, acc, 0, 0, 0);
            acc = __builtin_amdgcn_mfma_f32_16x16x32_bf16(ay, br, acc, 0, 0, 0);
            int o = ct * 16 + m;
            float bias = b2[MAXDEG * FOUT + o];
#pragma unroll
            for (int rg = 0; rg < 4; ++rg) {
                int rl = rbase + rg;
                int nn = row0 + rl;
                if (nn < N && !flg[rl]) out[(size_t)nn * FOUT + o] = acc[rg] + bias;
            }
        }
    } else {
        int wid = ((blockIdx.x - nbFast) * 256 + t) >> 6;
        int nw = (gridDim.x - nbFast) * 4;
        int lane = t & 63;
        int fcnt = *nflag;
        for (int i = wid; i < fcnt; i += nw) {
            int n = flist[i];
            int d = deg[n];
            float a0 = 0.f, a1 = 0.f;
            if (d > 0) {
                int e1 = cursor[n];
                gather16(y, adj, e1 - d, e1, d, lane, a0, a1);
                a0 += __shfl_xor(a0, 16); a1 += __shfl_xor(a1, 16);
                a0 += __shfl_xor(a0, 32); a1 += __shfl_xor(a1, 32);
            }
            const float* W2p  = W2full  + (size_t)d * (FHID * FOUT) + lane;
            const float* Wr2p = Wr2full + (size_t)d * (FHID * FOUT) + lane;
            unsigned int yw = *(const unsigned int*)(y + (size_t)n * FHID + (lane & 15) * 2);
            float acc = b2[d * FOUT + lane];
#pragma unroll
            for (int q = 0; q < 16; ++q) {
                float g0 = __shfl(a0, q);
                float g1 = __shfl(a1, q);
                unsigned int yq = __shfl(yw, q);
                acc += g0 * W2p[(2 * q) * FOUT] + g1 * W2p[(2 * q + 1) * FOUT]
                     + bflo(yq) * Wr2p[(2 * q) * FOUT] + bfhi(yq) * Wr2p[(2 * q + 1) * FOUT];
            }
            out[(size_t)n * FOUT + lane] = acc;
        }
    }
}

extern "C" void kernel_launch(void* const* d_in, const int* in_sizes, int n_in,
                              void* d_out, int out_size, void* d_ws, size_t ws_size,
                              hipStream_t stream) {
    const float* x   = (const float*)d_in[0];
    const int*   ei  = (const int*)d_in[1];   // int32, [2, E] flat
    const float* W1  = (const float*)d_in[2];
    const float* b1  = (const float*)d_in[3];
    const float* Wr1 = (const float*)d_in[4];
    const float* W2  = (const float*)d_in[5];
    const float* b2  = (const float*)d_in[6];
    const float* Wr2 = (const float*)d_in[7];

    int N = in_sizes[0] / FIN;
    int E = in_sizes[1] / 2;
    int K  = (N + 255) >> BSH;   // dst buckets

    char* ws = (char*)d_ws;
    size_t off = 0;
    auto alloc = [&](size_t bytes) {
        void* ptr = ws + off;
        off += (bytes + 511) / 512 * 512;
        return ptr;
    };
    int* deg              = (int*)alloc((size_t)N * sizeof(int));
    int* cursor           = (int*)alloc((size_t)N * sizeof(int));
    int* bcnt             = (int*)alloc((size_t)(K + 1) * sizeof(int));  // +1: nflag counter
    int* nflag            = bcnt + K;
    int* bstart           = (int*)alloc((size_t)K * sizeof(int));
    int* gcur             = (int*)alloc((size_t)K * sizeof(int));
    int* flist            = (int*)alloc((size_t)N * sizeof(int));
    int* adj              = (int*)alloc((size_t)E * sizeof(int));
    unsigned short* z10   = (unsigned short*)alloc((size_t)N * FHID * 2);
    unsigned short* r1    = (unsigned short*)alloc((size_t)N * FHID * 2);
    unsigned short* out1  = (unsigned short*)alloc((size_t)N * FHID * 2);
    // packed pairs (E*4B) and g (N*FHID*4B) share one region: pairs dead after k_passB2,
    // g first written by k_layer2g which runs later.
    size_t pairsB = (size_t)E * sizeof(unsigned int);
    size_t gB     = (size_t)N * FHID * sizeof(float);
    void* shared_region   = alloc(pairsB > gB ? pairsB : gB);
    float* g              = (float*)shared_region;
    unsigned int* pairs   = (unsigned int*)shared_region;
    unsigned short* wcat1 = (unsigned short*)alloc(64 * 128 * 2);
    unsigned short* wcat2 = (unsigned short*)alloc(128 * 32 * 2);

    float* out = (float*)d_out;

    (void)hipMemsetAsync(bcnt, 0, (size_t)(K + 1) * sizeof(int), stream);

    int nwgA = (E + ACHUNK - 1) / ACHUNK;
    k_bhistp<<<nwgA, 256, 0, stream>>>(ei, E, N, bcnt, W1, Wr1, W2, Wr2, wcat1, wcat2);
    k_scanb<<<1, 1024, 0, stream>>>(bcnt, K, bstart, gcur);
    k_passA<<<nwgA, 256, 0, stream>>>(ei, E, N, gcur, pairs);
    k_passB2<<<K, 256, 0, stream>>>(pairs, bstart, gcur, deg, cursor, adj, nflag, flist, N);

    int nb64 = (N + 63) / 64;     // MFMA kernels: 64 nodes per block
    int nb_pair = (N + 7) / 8;    // gather kernels: 2 nodes per wave, 4 waves per block
    const int FIXB = 512;         // fixup tail blocks (wave-per-flagged-node, grid-stride)

    k_pre1m<<<nb64, 256, 0, stream>>>(x, wcat1, b1, z10, r1, N);
    k_layer1x<<<nb_pair + FIXB, 256, 0, stream>>>(z10, r1, deg, cursor, adj,
                                                  x, W1, b1, Wr1, nflag, flist, out1,
                                                  N, nb_pair);
    k_layer2g<<<nb_pair, 256, 0, stream>>>(out1, deg, cursor, adj, g, N);
    k_post2x<<<nb64 + FIXB, 256, 0, stream>>>(g, out1, wcat2, b2, deg, cursor, adj,
                                              W2, Wr2, nflag, flist, out, N, nb64);
}